// Round 1
// 14021.994 us; speedup vs baseline: 1.2636x; 1.2636x over previous
//
#include <hip/hip_runtime.h>
#include <math.h>
#include <stdint.h>

// ---------------- problem constants ----------------
constexpr int kB = 4, kT = 1024, kE = 1024, kH = 16, kHS = 64;
constexpr int kDFF = 4096, kV = 32000, kL = 4;
constexpr int kRows = kB * kT;          // 4096 token rows
constexpr float kEps = 1e-5f;

typedef _Float16 f16;
typedef _Float16 f16x8 __attribute__((ext_vector_type(8)));
typedef float f32x4 __attribute__((ext_vector_type(4)));

#define AS1 __attribute__((address_space(1)))
#define AS3 __attribute__((address_space(3)))

// fp32 -> fp16 helpers (round-to-nearest-even via scalar cast)
__device__ __forceinline__ ushort f2h(float f) {
  f16 h = (f16)f;
  return __builtin_bit_cast(ushort, h);
}
__device__ __forceinline__ void fsplit(float f, ushort& hi, ushort& lo) {
  f16 h = (f16)f;
  hi = __builtin_bit_cast(ushort, h);
  f16 l = (f16)(f - (float)h);
  lo = __builtin_bit_cast(ushort, l);
}

// async global->LDS, 16B/lane; LDS dest = wave-uniform base + lane*16,
// global source is per-lane (m173 pattern).
__device__ __forceinline__ void gload_lds16(const ushort* g, ushort* l) {
  __builtin_amdgcn_global_load_lds((AS1 void*)(uintptr_t)g, (AS3 void*)l, 16,
                                   0, 0);
}

// ---------------- wave/block reduction helpers ----------------
__device__ __forceinline__ float wave_sum(float v) {
#pragma unroll
  for (int o = 32; o > 0; o >>= 1) v += __shfl_down(v, o, 64);
  return v;
}
__device__ __forceinline__ float wave_max(float v) {
#pragma unroll
  for (int o = 32; o > 0; o >>= 1) v = fmaxf(v, __shfl_down(v, o, 64));
  return v;
}

// ---------------- embedding: x = tok_emb[index] + pos_emb[:T] ----------------
__global__ __launch_bounds__(256) void embed_kernel(
    const int* __restrict__ index, const float* __restrict__ tok,
    const float* __restrict__ pos, float* __restrict__ x) {
  int r = blockIdx.x;
  int t = r & (kT - 1);
  int tokid = index[r];
  const float4* tp = (const float4*)(tok + (size_t)tokid * kE);
  const float4* pp = (const float4*)(pos + (size_t)t * kE);
  float4* xp = (float4*)(x + (size_t)r * kE);
  int c = threadIdx.x;
  float4 a = tp[c], b = pp[c];
  xp[c] = make_float4(a.x + b.x, a.y + b.y, a.z + b.z, a.w + b.w);
}

// ---------------- layernorm -> fp16 hi/lo split output ----------------
__global__ __launch_bounds__(256) void lnh_kernel(
    const float* __restrict__ x, const float* __restrict__ g,
    const float* __restrict__ b, ushort* __restrict__ ohi,
    ushort* __restrict__ olo) {
  int r = blockIdx.x;
  int tid = threadIdx.x;
  __shared__ float red[4];
  float4 v = ((const float4*)(x + (size_t)r * kE))[tid];
  float s = v.x + v.y + v.z + v.w;
  float ws = wave_sum(s);
  if ((tid & 63) == 0) red[tid >> 6] = ws;
  __syncthreads();
  float mu = (red[0] + red[1] + red[2] + red[3]) * (1.0f / kE);
  __syncthreads();
  float dx0 = v.x - mu, dx1 = v.y - mu, dx2 = v.z - mu, dx3 = v.w - mu;
  float sq = dx0 * dx0 + dx1 * dx1 + dx2 * dx2 + dx3 * dx3;
  float wv = wave_sum(sq);
  if ((tid & 63) == 0) red[tid >> 6] = wv;
  __syncthreads();
  float var = (red[0] + red[1] + red[2] + red[3]) * (1.0f / kE);
  float inv = rsqrtf(var + kEps);
  float4 gg = ((const float4*)g)[tid];
  float4 bb = ((const float4*)b)[tid];
  float o0 = dx0 * inv * gg.x + bb.x;
  float o1 = dx1 * inv * gg.y + bb.y;
  float o2 = dx2 * inv * gg.z + bb.z;
  float o3 = dx3 * inv * gg.w + bb.w;
  ushort4 hi, lo;
  fsplit(o0, hi.x, lo.x);
  fsplit(o1, hi.y, lo.y);
  fsplit(o2, hi.z, lo.z);
  fsplit(o3, hi.w, lo.w);
  ((ushort4*)(ohi + (size_t)r * kE))[tid] = hi;
  ((ushort4*)(olo + (size_t)r * kE))[tid] = lo;
}

// ---------------- weight convert: fp32 [K][N] -> frag-ordered fp16 tiles ----
// Output layout: tile (nt, kt) is 4096 halves at ((nt*ksteps)+kt)*4096.
// Within a tile, chunk c (16B = 8 halves): col = (c>>6)*16 + (c&15),
// k = ((c>>4)&3)*8 + j  -> exactly the 16x16x32 B-operand order so the GEMM
// can stage it with linear global_load_lds and read with ds_read_b128.
__global__ __launch_bounds__(256) void wconv_kernel(
    const float* __restrict__ W, ushort* __restrict__ out, int ldW,
    int ksteps) {
  __shared__ float Tt[128][36];
  int nt = blockIdx.x, kt = blockIdx.y;
  int tid = threadIdx.x;
  const float* src = W + (size_t)kt * 32 * ldW + (size_t)nt * 128;
#pragma unroll
  for (int p = 0; p < 4; ++p) {
    int idx = tid + p * 256;
    int rr = idx >> 5, cc = (idx & 31) * 4;
    float4 vv = *(const float4*)(src + (size_t)rr * ldW + cc);
    Tt[cc + 0][rr] = vv.x;
    Tt[cc + 1][rr] = vv.y;
    Tt[cc + 2][rr] = vv.z;
    Tt[cc + 3][rr] = vv.w;
  }
  __syncthreads();
  ushort* dst = out + ((size_t)nt * ksteps + kt) * 4096;
#pragma unroll
  for (int p = 0; p < 2; ++p) {
    int c = tid + p * 256;
    int col = ((c >> 6) << 4) + (c & 15);
    int k8 = ((c >> 4) & 3) * 8;
    uint4 wv;
    wv.x = (uint)f2h(Tt[col][k8 + 0]) | ((uint)f2h(Tt[col][k8 + 1]) << 16);
    wv.y = (uint)f2h(Tt[col][k8 + 2]) | ((uint)f2h(Tt[col][k8 + 3]) << 16);
    wv.z = (uint)f2h(Tt[col][k8 + 4]) | ((uint)f2h(Tt[col][k8 + 5]) << 16);
    wv.w = (uint)f2h(Tt[col][k8 + 6]) | ((uint)f2h(Tt[col][k8 + 7]) << 16);
    *(uint4*)(dst + (size_t)c * 8) = wv;
  }
}

// ---------------- MFMA GEMM: C = (Ah+Al) @ Bf16  (fp16 one-side split) -----
// A: row-major fp16 hi/lo [M][K].  B: frag-ordered fp16 tiles (wconv).
// 128x128 tile, BK=32, 4 waves (2x2), per wave 4x4 frags of 16x16x32.
// Out mode A (C != null): fp32 C (+bias)(+resid), ld = ldC.
// Out mode B (C == null): fp16 hi/lo Oh/Ol (+bias)(relu), ld = ldC.
__global__ __launch_bounds__(256) void mgemm_kernel(
    const ushort* __restrict__ Ah, const ushort* __restrict__ Al,
    const ushort* __restrict__ Bf, float* __restrict__ C, int ldC,
    ushort* __restrict__ Oh, ushort* __restrict__ Ol,
    const float* __restrict__ bias, const float* __restrict__ resid, int M,
    int K, int relu) {
  __shared__ ushort lsA[8192];   // hi [0,4096) halves, lo [4096,8192)
  __shared__ ushort lsB[4096];
  int tid = threadIdx.x;
  int w = tid >> 6, lane = tid & 63;
  int wr = w >> 1, wc = w & 1;
  int bm = blockIdx.y * 128;
  int ksteps = K >> 5;

  // per-lane A source offsets for the wave's two chunk-sets
  size_t aoff[2];
  int cb[2];
#pragma unroll
  for (int s = 0; s < 2; ++s) {
    int c = s * 256 + w * 64 + lane;
    int row = ((c >> 6) << 4) + (c & 15);
    int k8 = ((c >> 4) & 3) * 8;
    aoff[s] = (size_t)(bm + row) * K + k8;
    cb[s] = (s * 256 + w * 64) * 8;   // wave-uniform ushort offset
  }
  const ushort* Bt = Bf + (size_t)blockIdx.x * ksteps * 4096;

  f32x4 zero = {0.f, 0.f, 0.f, 0.f};
  f32x4 acc[4][4];
#pragma unroll
  for (int i = 0; i < 4; ++i)
#pragma unroll
    for (int j = 0; j < 4; ++j) acc[i][j] = zero;

  for (int kt = 0; kt < ksteps; ++kt) {
    int k0 = kt * 32;
    const ushort* bsrc = Bt + (size_t)kt * 4096;
#pragma unroll
    for (int s = 0; s < 2; ++s) {
      gload_lds16(Ah + aoff[s] + k0, &lsA[cb[s]]);
      gload_lds16(Al + aoff[s] + k0, &lsA[4096 + cb[s]]);
      gload_lds16(bsrc + cb[s] + lane * 8, &lsB[cb[s]]);
    }
    __syncthreads();   // drains vmcnt + lgkmcnt
    f16x8 ah[4], al[4], bfr[4];
#pragma unroll
    for (int m = 0; m < 4; ++m) {
      int fi = ((wr * 4 + m) * 64 + lane) * 8;
      ah[m] = *(const f16x8*)&lsA[fi];
      al[m] = *(const f16x8*)&lsA[4096 + fi];
    }
#pragma unroll
    for (int n = 0; n < 4; ++n) {
      int fi = ((wc * 4 + n) * 64 + lane) * 8;
      bfr[n] = *(const f16x8*)&lsB[fi];
    }
#pragma unroll
    for (int m = 0; m < 4; ++m)
#pragma unroll
      for (int n = 0; n < 4; ++n) {
        acc[m][n] =
            __builtin_amdgcn_mfma_f32_16x16x32_f16(ah[m], bfr[n], acc[m][n], 0, 0, 0);
        acc[m][n] =
            __builtin_amdgcn_mfma_f32_16x16x32_f16(al[m], bfr[n], acc[m][n], 0, 0, 0);
      }
    __syncthreads();
  }

  // epilogue: D lane mapping col = lane&15, row = (lane>>4)*4 + reg
  int colbase = blockIdx.x * 128 + wc * 64 + (lane & 15);
  int rowoff = (lane >> 4) * 4;
#pragma unroll
  for (int m = 0; m < 4; ++m) {
    int gm0 = bm + wr * 64 + m * 16 + rowoff;
#pragma unroll
    for (int n = 0; n < 4; ++n) {
      int col = colbase + n * 16;
      float bv = bias ? bias[col] : 0.f;
#pragma unroll
      for (int j = 0; j < 4; ++j) {
        size_t idx = (size_t)(gm0 + j) * ldC + col;
        float v = acc[m][n][j] + bv;
        if (C) {
          if (resid) v += resid[idx];
          C[idx] = v;
        } else {
          if (relu) v = fmaxf(v, 0.f);
          ushort h, l;
          fsplit(v, h, l);
          Oh[idx] = h;
          Ol[idx] = l;
        }
      }
    }
  }
}

// ---------------- causal attention, block per (b,h, 8-query tile) ----------
// Scores for the whole row materialized in LDS; softmax; P.V.
// Output written as fp16 hi/lo (feeds the O-projection MFMA GEMM).
__global__ __launch_bounds__(256) void fattn_kernel(
    const float* __restrict__ q, const float* __restrict__ k,
    const float* __restrict__ v, ushort* __restrict__ ohi,
    ushort* __restrict__ olo) {
  int qt = blockIdx.x;           // 0..127
  int bh = blockIdx.y;           // 0..63
  int b = bh >> 4, h = bh & 15;
  int qbase = qt * 8;
  int nk = qbase + 8;
  int tid = threadIdx.x;
  __shared__ float Q[8][64];
  __shared__ float S[8][1032];   // pad 8 floats: spreads row starts over banks
  __shared__ float rstat[8];
  const size_t base = (size_t)b * kT * kE + (size_t)h * kHS;
  if (tid < 128) {
    int r = tid >> 4, c4 = (tid & 15) * 4;
    *(float4*)&Q[r][c4] =
        *(const float4*)(q + base + (size_t)(qbase + r) * kE + c4);
  }
  __syncthreads();
  int qi = tid >> 5, ks = tid & 31;   // 32 threads per query row
  int qrow = qbase + qi;
  // ---- scores
  for (int kk = ks; kk < nk; kk += 32) {
    const float* kr = k + base + (size_t)kk * kE;
    float d0 = 0.f, d1 = 0.f;
#pragma unroll
    for (int c = 0; c < 32; c += 4) {
      float4 a = *(const float4*)(kr + c);
      float4 bq = *(const float4*)&Q[qi][c];
      d0 = fmaf(bq.x, a.x, d0);
      d0 = fmaf(bq.y, a.y, d0);
      d0 = fmaf(bq.z, a.z, d0);
      d0 = fmaf(bq.w, a.w, d0);
      float4 a2 = *(const float4*)(kr + 32 + c);
      float4 bq2 = *(const float4*)&Q[qi][32 + c];
      d1 = fmaf(bq2.x, a2.x, d1);
      d1 = fmaf(bq2.y, a2.y, d1);
      d1 = fmaf(bq2.z, a2.z, d1);
      d1 = fmaf(bq2.w, a2.w, d1);
    }
    S[qi][kk] = (d0 + d1) * 0.125f;   // HS^-0.5
  }
  __syncthreads();
  // ---- softmax over row (32-lane group per row)
  float m = -1e30f;
  for (int kk = ks; kk <= qrow; kk += 32) m = fmaxf(m, S[qi][kk]);
#pragma unroll
  for (int o = 1; o < 32; o <<= 1) m = fmaxf(m, __shfl_xor(m, o, 64));
  float ls = 0.f;
  for (int kk = ks; kk < nk; kk += 32) {
    float p = (kk <= qrow) ? __expf(S[qi][kk] - m) : 0.f;
    S[qi][kk] = p;
    ls += p;
  }
#pragma unroll
  for (int o = 1; o < 32; o <<= 1) ls += __shfl_xor(ls, o, 64);
  if (ks == 0) rstat[qi] = 1.0f / ls;
  __syncthreads();
  // ---- P.V : thread (qi, 2 output dims)
  int d0c = ks * 2;
  float a0 = 0.f, a1 = 0.f, b0 = 0.f, b1 = 0.f;
  int kk = 0;
  for (; kk + 1 < nk; kk += 2) {
    float p0 = S[qi][kk], p1 = S[qi][kk + 1];
    const float* vp = v + base + (size_t)kk * kE + d0c;
    float2 x0 = *(const float2*)vp;
    float2 x1 = *(const float2*)(vp + kE);
    a0 = fmaf(p0, x0.x, a0);
    a1 = fmaf(p0, x0.y, a1);
    b0 = fmaf(p1, x1.x, b0);
    b1 = fmaf(p1, x1.y, b1);
  }
  if (kk < nk) {
    float p0 = S[qi][kk];
    float2 x0 = *(const float2*)(v + base + (size_t)kk * kE + d0c);
    a0 = fmaf(p0, x0.x, a0);
    a1 = fmaf(p0, x0.y, a1);
  }
  float inv = rstat[qi];
  float r0 = (a0 + b0) * inv, r1 = (a1 + b1) * inv;
  size_t oidx = base + (size_t)qrow * kE + d0c;
  ushort h0, l0, h1, l1;
  fsplit(r0, h0, l0);
  fsplit(r1, h1, l1);
  ushort2 hh, ll;
  hh.x = h0; hh.y = h1;
  ll.x = l0; ll.y = l1;
  *(ushort2*)(ohi + oidx) = hh;
  *(ushort2*)(olo + oidx) = ll;
}

// ---------------- loss stage 1: per-row -logp[target] ----------------
__global__ __launch_bounds__(256) void loss_row_kernel(
    const float* __restrict__ logits, const int* __restrict__ targets,
    float* __restrict__ rowloss) {
  int r = blockIdx.x;
  int tid = threadIdx.x;
  const float4* lr = (const float4*)(logits + (size_t)r * kV);
  __shared__ float red[4];
  float lmax = -1e30f;
  for (int c = tid; c < kV / 4; c += 256) {
    float4 v = lr[c];
    lmax = fmaxf(lmax, fmaxf(fmaxf(v.x, v.y), fmaxf(v.z, v.w)));
  }
  float wm = wave_max(lmax);
  if ((tid & 63) == 0) red[tid >> 6] = wm;
  __syncthreads();
  float bmax = fmaxf(fmaxf(red[0], red[1]), fmaxf(red[2], red[3]));
  __syncthreads();
  float lsum = 0.0f;
  for (int c = tid; c < kV / 4; c += 256) {
    float4 v = lr[c];
    lsum += expf(v.x - bmax) + expf(v.y - bmax) + expf(v.z - bmax) +
            expf(v.w - bmax);
  }
  float ws = wave_sum(lsum);
  if ((tid & 63) == 0) red[tid >> 6] = ws;
  __syncthreads();
  if (tid == 0) {
    float bsum = red[0] + red[1] + red[2] + red[3];
    float tgt = logits[(size_t)r * kV + targets[r]];
    rowloss[r] = -(tgt - bmax - logf(bsum));
  }
}

// ---------------- loss stage 2: mean over 4096 rows ----------------
__global__ __launch_bounds__(256) void loss_final_kernel(
    const float* __restrict__ rowloss, float* __restrict__ out) {
  int tid = threadIdx.x;
  __shared__ float red[4];
  float s = 0.0f;
  for (int r = tid; r < kRows; r += 256) s += rowloss[r];
  float ws = wave_sum(s);
  if ((tid & 63) == 0) red[tid >> 6] = ws;
  __syncthreads();
  if (tid == 0)
    out[0] = (red[0] + red[1] + red[2] + red[3]) * (1.0f / kRows);
}

// ---------------- host-side orchestration ----------------
extern "C" void kernel_launch(void* const* d_in, const int* in_sizes, int n_in,
                              void* d_out, int out_size, void* d_ws,
                              size_t ws_size, hipStream_t stream) {
  const int* index = (const int*)d_in[0];
  const int* targets = (const int*)d_in[1];
  const float* tok_emb = (const float*)d_in[2];
  const float* pos_emb = (const float*)d_in[3];
  const float* Wq = (const float*)d_in[4];
  const float* Wk = (const float*)d_in[5];
  const float* Wv = (const float*)d_in[6];
  const float* Wo = (const float*)d_in[7];
  const float* bo = (const float*)d_in[8];
  const float* ln0_g = (const float*)d_in[9];
  const float* ln0_b = (const float*)d_in[10];
  const float* ln1_g = (const float*)d_in[11];
  const float* ln1_b = (const float*)d_in[12];
  const float* W1 = (const float*)d_in[13];
  const float* b1 = (const float*)d_in[14];
  const float* W2 = (const float*)d_in[15];
  const float* b2 = (const float*)d_in[16];
  const float* fln_g = (const float*)d_in[17];
  const float* fln_b = (const float*)d_in[18];
  const float* lmh_W = (const float*)d_in[19];
  const float* lmh_b = (const float*)d_in[20];

  float* logits = (float*)d_out;                       // [4096, 32000]
  float* loss = logits + (size_t)kRows * kV;

  // workspace layout (identical footprint to the verified baseline):
  // x(f32) | h_hi/h_lo(f16) | qb kb vb(f32) | o_hi/o_lo(f16) | rowloss
  // ff hi/lo (f16, 4096x4096 each) aliases qb..o region exactly.
  const size_t RE = (size_t)kRows * kE;
  float* x = (float*)d_ws;
  ushort* h_hi = (ushort*)(x + RE);
  ushort* h_lo = h_hi + RE;
  float* qb = (float*)(h_lo + RE);
  float* kb = qb + RE;
  float* vb = kb + RE;
  ushort* o_hi = (ushort*)(vb + RE);
  ushort* o_lo = o_hi + RE;
  ushort* ff_hi = (ushort*)qb;
  ushort* ff_lo = ff_hi + (size_t)kRows * kDFF;
  float* rowloss = (float*)(o_lo + RE);

  // fp16 frag-ordered weight scratch lives in the logits buffer (dead until
  // the lm_head GEMM); 4 layers x 12.58M halves = 96 MB << 524 MB.
  ushort* wf = (ushort*)logits;
  const size_t WEE = (size_t)kE * kE;
  const size_t WED = (size_t)kE * kDFF;
  const size_t perL = 4 * WEE + 2 * WED;

  dim3 blk(256);
  dim3 gE(kE / 128, kRows / 128);
  dim3 gF(kDFF / 128, kRows / 128);

  // ---- weight conversion passes (per launch; ~160 MB of writes total)
  for (int l = 0; l < kL; ++l) {
    ushort* wq_f = wf + (size_t)l * perL;
    ushort* wk_f = wq_f + WEE;
    ushort* wv_f = wk_f + WEE;
    ushort* wo_f = wv_f + WEE;
    ushort* w1_f = wo_f + WEE;
    ushort* w2_f = w1_f + WED;
    wconv_kernel<<<dim3(kE / 128, kE / 32), blk, 0, stream>>>(
        Wq + (size_t)l * WEE, wq_f, kE, kE / 32);
    wconv_kernel<<<dim3(kE / 128, kE / 32), blk, 0, stream>>>(
        Wk + (size_t)l * WEE, wk_f, kE, kE / 32);
    wconv_kernel<<<dim3(kE / 128, kE / 32), blk, 0, stream>>>(
        Wv + (size_t)l * WEE, wv_f, kE, kE / 32);
    wconv_kernel<<<dim3(kE / 128, kE / 32), blk, 0, stream>>>(
        Wo + (size_t)l * WEE, wo_f, kE, kE / 32);
    wconv_kernel<<<dim3(kDFF / 128, kE / 32), blk, 0, stream>>>(
        W1 + (size_t)l * WED, w1_f, kDFF, kE / 32);
    wconv_kernel<<<dim3(kE / 128, kDFF / 32), blk, 0, stream>>>(
        W2 + (size_t)l * WED, w2_f, kE, kDFF / 32);
  }

  embed_kernel<<<kRows, blk, 0, stream>>>(index, tok_emb, pos_emb, x);

  for (int l = 0; l < kL; ++l) {
    ushort* wq_f = wf + (size_t)l * perL;
    ushort* wk_f = wq_f + WEE;
    ushort* wv_f = wk_f + WEE;
    ushort* wo_f = wv_f + WEE;
    ushort* w1_f = wo_f + WEE;
    ushort* w2_f = w1_f + WED;

    lnh_kernel<<<kRows, blk, 0, stream>>>(x, ln0_g + l * kE, ln0_b + l * kE,
                                          h_hi, h_lo);
    mgemm_kernel<<<gE, blk, 0, stream>>>(h_hi, h_lo, wq_f, qb, kE, nullptr,
                                         nullptr, nullptr, nullptr, kRows, kE,
                                         0);
    mgemm_kernel<<<gE, blk, 0, stream>>>(h_hi, h_lo, wk_f, kb, kE, nullptr,
                                         nullptr, nullptr, nullptr, kRows, kE,
                                         0);
    mgemm_kernel<<<gE, blk, 0, stream>>>(h_hi, h_lo, wv_f, vb, kE, nullptr,
                                         nullptr, nullptr, nullptr, kRows, kE,
                                         0);
    fattn_kernel<<<dim3(kT / 8, kB * kH), blk, 0, stream>>>(qb, kb, vb, o_hi,
                                                            o_lo);
    mgemm_kernel<<<gE, blk, 0, stream>>>(o_hi, o_lo, wo_f, x, kE, nullptr,
                                         nullptr, bo + l * kE, x, kRows, kE,
                                         0);
    lnh_kernel<<<kRows, blk, 0, stream>>>(x, ln1_g + l * kE, ln1_b + l * kE,
                                          h_hi, h_lo);
    mgemm_kernel<<<gF, blk, 0, stream>>>(h_hi, h_lo, w1_f, nullptr, kDFF,
                                         ff_hi, ff_lo, b1 + l * kDFF, nullptr,
                                         kRows, kE, 1);
    mgemm_kernel<<<gE, blk, 0, stream>>>(ff_hi, ff_lo, w2_f, x, kE, nullptr,
                                         nullptr, b2 + l * kE, x, kRows, kDFF,
                                         0);
  }

  lnh_kernel<<<kRows, blk, 0, stream>>>(x, fln_g, fln_b, h_hi, h_lo);

  // lm_head in two N=16000 halves; fp16 weight scratch in the freed q/k/v
  // region (32.8 MB <= 48 MB).
  ushort* lscr = (ushort*)qb;
  for (int hf = 0; hf < 2; ++hf) {
    wconv_kernel<<<dim3(16000 / 128, kE / 32), blk, 0, stream>>>(
        lmh_W + hf * 16000, lscr, kV, kE / 32);
    mgemm_kernel<<<dim3(16000 / 128, kRows / 128), blk, 0, stream>>>(
        h_hi, h_lo, lscr, logits + hf * 16000, kV, nullptr, nullptr,
        lmh_b + hf * 16000, nullptr, kRows, kE, 0);
  }

  loss_row_kernel<<<kRows, blk, 0, stream>>>(logits, targets, rowloss);
  loss_final_kernel<<<1, blk, 0, stream>>>(rowloss, loss);
}